// Round 17
// baseline (176.659 us; speedup 1.0000x reference)
//
#include <hip/hip_runtime.h>

typedef __attribute__((ext_vector_type(8))) short bhalf8;
typedef __attribute__((ext_vector_type(4))) float floatx4;

#define NF 6  // freq_list = [1,103,205,307,409,511] -> periods [2,104,206,308,410,512]

__device__ __forceinline__ unsigned short f2bf(float f) {
  unsigned u = __float_as_uint(f);
  u += 0x7FFFu + ((u >> 16) & 1u);
  return (unsigned short)(u >> 16);
}
__device__ __forceinline__ float bf2f(unsigned h) {
  return __uint_as_float(h << 16);
}

// ------- kernel 1: period weights (6-freq DFT + softmax) + fused W-prep ----
// prep path emits the 16x16-MFMA lane-linear B-fragment image (R9 layout):
// chunk task = ((didj*2+kk)*4+nt)*64 + ln holds
//   Wt[fo = nt*16+(ln&15)][fi = kk*32+(ln>>4)*8 + 0..7]
// so conv's bfr load = base + lane*16 -> ONE coalesced 1KB transaction.
__global__ __launch_bounds__(512) void pw_kernel(const float* __restrict__ x,
                                                 float* __restrict__ pwbuf,
                                                 const float* __restrict__ W,
                                                 unsigned short* __restrict__ wt2) {
  const int tid = threadIdx.x;
  if (blockIdx.x >= 256) {  // ---- prep_w path ----
    if (tid < 256) {
      int task = (blockIdx.x - 256) * 256 + tid;  // 9*2*4*64 = 4608 tasks
      int ln = task & 63;
      int nt = (task >> 6) & 3;
      int kk = (task >> 8) & 1;
      int didj = task >> 9;
      int fo = nt * 16 + (ln & 15);
      int fi0 = kk * 32 + (ln >> 4) * 8;
      bhalf8 pk;
#pragma unroll
      for (int j = 0; j < 8; ++j)
        pk[j] = (short)f2bf(W[(size_t)(didj * 64 + fi0 + j) * 64 + fo]);
      *(bhalf8*)((char*)wt2 + (size_t)task * 16) = pk;
    }
    return;
  }
  const int bh = blockIdx.x;
  const int w = tid >> 6;
  const int f = tid & 63;
  const int t0w = w * 128;
  const float* xb = x + (size_t)bh * 65536 + f;

  const float STEP = -6.283185307179586f / 1024.0f;
  float re[NF], im[NF], c[NF], s[NF], ck[NF], sk[NF];
#pragma unroll
  for (int k = 0; k < NF; ++k) {
    int freq = 1 + 102 * k;
    int ph0 = (freq * t0w) & 1023;
    __sincosf((float)ph0 * STEP, &s[k], &c[k]);
    __sincosf((float)freq * STEP, &sk[k], &ck[k]);
    re[k] = 0.f;
    im[k] = 0.f;
  }
#pragma unroll 4
  for (int t = 0; t < 128; ++t) {
    float v = xb[(size_t)(t0w + t) * 64];
#pragma unroll
    for (int k = 0; k < NF; ++k) {
      re[k] = fmaf(v, c[k], re[k]);
      im[k] = fmaf(v, s[k], im[k]);
      float cn = fmaf(c[k], ck[k], -s[k] * sk[k]);
      float sn = fmaf(c[k], sk[k], s[k] * ck[k]);
      c[k] = cn;
      s[k] = sn;
    }
  }
  __shared__ float part[8][NF][64][2];  // 24 KB
#pragma unroll
  for (int k = 0; k < NF; ++k) {
    part[w][k][f][0] = re[k];
    part[w][k][f][1] = im[k];
  }
  __syncthreads();
  if (tid < 64) {
    float sm[NF];
#pragma unroll
    for (int k = 0; k < NF; ++k) {
      float rr = 0.f, ii = 0.f;
#pragma unroll
      for (int ww = 0; ww < 8; ++ww) {
        rr += part[ww][k][tid][0];
        ii += part[ww][k][tid][1];
      }
      float amp = sqrtf(rr * rr + ii * ii);
#pragma unroll
      for (int off = 32; off > 0; off >>= 1) amp += __shfl_xor(amp, off);
      sm[k] = amp * (1.0f / 64.0f);
    }
    if (tid == 0) {
      float m = sm[0];
#pragma unroll
      for (int i = 1; i < NF; ++i) m = fmaxf(m, sm[i]);
      float e[NF], ssum = 0.f;
#pragma unroll
      for (int i = 0; i < NF; ++i) {
        e[i] = __expf(sm[i] - m);
        ssum += e[i];
      }
      float inv = 1.0f / ssum;
#pragma unroll
      for (int i = 0; i < NF; ++i) pwbuf[bh * NF + i] = e[i] * inv;
    }
  }
}

// ---------------- kernel 3: fused 6-period conv + relu + weighted sum + x --
// 3-WAVES/SIMD design: 256-thread blocks (4 waves), paired 64-row halves
// [t0w,t0w+64) u [512+t0w,+64); wave = 32 rows x 64 cols (g=wid>>1, wr=wid&1).
// __launch_bounds__(256,3) -> reg cap 170, 3 blocks/CU = 3 waves/SIMD.
// Fits via: 3 passes x 2 live kp (acc[2][2][4] = 64 AGPR), fin bf16-packed
// (16 regs, R9-verified), B-frags from L2-resident lane-linear wt2 (no W LDS;
// coalesced 1KB loads). LDS = win[2][88] + zrow = 22.7 KB. A-reads keep the
// R10 swizzled pattern. Masked edge taps redirect the A-read to a zero row.
__global__ __launch_bounds__(256, 3) void conv_kernel(
    const float* __restrict__ x, const unsigned short* __restrict__ wt2,
    const float* __restrict__ bias, const float* __restrict__ pwbuf,
    float* __restrict__ out) {
  __shared__ __align__(16) unsigned short win[2][88 * 64];  // 22528 B
  __shared__ __align__(16) unsigned short zrow[64];         // 128 B

  const int tid = threadIdx.x;
  const int bh = blockIdx.y;
  const int t0w = blockIdx.x * 64;
  const float* xbh = x + (size_t)bh * (1024 * 64);

  // ---- stage both windows: window w row trel <-> t' = w*512 + t0w - 12 + trel
  {
    const int fi0 = (tid & 7) * 8;
#pragma unroll
    for (int w = 0; w < 2; ++w) {
      int tbase = w * 512 + t0w - 12;
#pragma unroll
      for (int rr = 0; rr < 3; ++rr) {
        int trel = (tid >> 3) + rr * 32;
        if (trel < 88) {
          int tp = tbase + trel;
          float va[8];
          if ((unsigned)tp < 1024u) {
            const float4* src = (const float4*)(xbh + (size_t)tp * 64 + fi0);
            float4 u0 = src[0], u1 = src[1];
            va[0] = u0.x; va[1] = u0.y; va[2] = u0.z; va[3] = u0.w;
            va[4] = u1.x; va[5] = u1.y; va[6] = u1.z; va[7] = u1.w;
          } else {
#pragma unroll
            for (int j = 0; j < 8; ++j) va[j] = 0.f;
          }
          bhalf8 pk;
#pragma unroll
          for (int j = 0; j < 8; ++j) pk[j] = (short)f2bf(va[j]);
          *(bhalf8*)((char*)win[w] + (trel << 7) +
                     ((fi0 * 2) ^ ((trel & 7) << 4))) = pk;
        }
      }
    }
    if (tid < 8) *(bhalf8*)((char*)zrow + tid * 16) = (bhalf8)0;
  }
  __syncthreads();  // the only barrier

  const int l15 = tid & 15;
  const int l4x16 = ((tid >> 4) & 3) * 16;
  const int lane = tid & 63;
  const int wid = tid >> 6;
  const int g = wid >> 1;          // which t-half this wave outputs
  const int wr = wid & 1;          // 32-row group within the half
  const int rtb = g * 512 + t0w + wr * 32;
  const int dOther = g ? 0 : 2;    // the di whose kp0 tap is in partner window
  const char* ownw = (const char*)win[g];
  const char* othw = (const char*)win[1 - g];
  const char* zb = (const char*)zrow;

  // pre-packed per-lane edge bits: bit kp set iff col j==0 (eLo) / j==q-1 (eHi)
  const int rt0 = rtb + l15, rt1 = rt0 + 16;
  int eLo0 = 0, eHi0 = 0, eLo1 = 0, eHi1 = 0;
  {
    int j0, j1;
    j0 = rt0 & 511; j1 = rt1 & 511;
    eLo0 |= (j0 == 0) << 0;   eHi0 |= (j0 == 511) << 0;
    eLo1 |= (j1 == 0) << 0;   eHi1 |= (j1 == 511) << 0;
    j0 = rt0 % 10;  j1 = rt1 % 10;
    eLo0 |= (j0 == 0) << 1;   eHi0 |= (j0 == 9) << 1;
    eLo1 |= (j1 == 0) << 1;   eHi1 |= (j1 == 9) << 1;
    j0 = rt0 % 5;   j1 = rt1 % 5;
    eLo0 |= (j0 == 0) << 2;   eHi0 |= (j0 == 4) << 2;
    eLo1 |= (j1 == 0) << 2;   eHi1 |= (j1 == 4) << 2;
    j0 = rt0 & 3;   j1 = rt1 & 3;
    eLo0 |= (j0 == 0) << 3;   eHi0 |= (j0 == 3) << 3;
    eLo1 |= (j1 == 0) << 3;   eHi1 |= (j1 == 3) << 3;
    j0 = rt0 % 3;   j1 = rt1 % 3;
    eLo0 |= (j0 == 0) << 4;   eHi0 |= (j0 == 2) << 4;
    eLo1 |= (j1 == 0) << 4;   eHi1 |= (j1 == 2) << 4;
    j0 = rt0 & 1;   j1 = rt1 & 1;
    eLo0 |= (j0 == 0) << 5;   eHi0 |= (j0 == 1) << 5;
    eLo1 |= (j1 == 0) << 5;   eHi1 |= (j1 == 1) << 5;
  }

  float bv[4];
#pragma unroll
  for (int nt = 0; nt < 4; ++nt) bv[nt] = bias[nt * 16 + l15];

  // fin packed as bf16 pairs: finp[mt][nt][rp] = (bf16(r=2rp+1)<<16)|bf16(2rp)
  unsigned finp[2][4][2];
#pragma unroll
  for (int mt = 0; mt < 2; ++mt)
#pragma unroll
    for (int nt = 0; nt < 4; ++nt)
#pragma unroll
      for (int rp = 0; rp < 2; ++rp) finp[mt][nt][rp] = 0u;

  const int base = wr * 32 + l15;

#define MFMA16(A, B, C) __builtin_amdgcn_mfma_f32_16x16x32_bf16((A), (B), (C), 0, 0, 0)

#define DO_TAP(C, KP, BUFBASE, R0)                                            \
  {                                                                           \
    int r0_ = (R0);                                                           \
    const char* pa0 = (((bad0 >> (KP)) & 1) == 0)                             \
                          ? (const char*)(BUFBASE) + (r0_ << 7) : zb;         \
    const char* pa1 = (((bad1 >> (KP)) & 1) == 0)                             \
                          ? (const char*)(BUFBASE) + ((r0_ + 16) << 7) : zb;  \
    int sw_ = (r0_ & 7) << 4;                                                 \
    _Pragma("unroll") for (int kk = 0; kk < 2; ++kk) {                        \
      int kb = kk * 64 + l4x16;                                               \
      bhalf8 a0 = *(const bhalf8*)(pa0 + (kb ^ sw_));                         \
      bhalf8 a1 = *(const bhalf8*)(pa1 + (kb ^ sw_));                         \
      _Pragma("unroll") for (int nt = 0; nt < 4; ++nt) {                      \
        acc[C][0][nt] = MFMA16(a0, bfr[kk][nt], acc[C][0][nt]);               \
        acc[C][1][nt] = MFMA16(a1, bfr[kk][nt], acc[C][1][nt]);               \
      }                                                                       \
    }                                                                         \
  }

  // lane-linear coalesced B-fragment loads straight from L2-resident wt2
#define LOAD_BFR(DI, DJ)                                                      \
  bhalf8 bfr[2][4];                                                           \
  {                                                                           \
    const char* wb = (const char*)wt2 + (((size_t)((DI) * 3 + (DJ))) << 13) + \
                     (lane << 4);                                             \
    _Pragma("unroll") for (int kk = 0; kk < 2; ++kk)                          \
        _Pragma("unroll") for (int nt = 0; nt < 4; ++nt)                      \
            bfr[kk][nt] = *(const bhalf8*)(wb + ((kk * 4 + nt) << 10));       \
  }

#define FOLDP(C, KP)                                                          \
  {                                                                           \
    const float pw_ = pwbuf[bh * NF + (KP)];                                  \
    _Pragma("unroll") for (int mt = 0; mt < 2; ++mt)                          \
        _Pragma("unroll") for (int nt = 0; nt < 4; ++nt)                      \
            _Pragma("unroll") for (int rp = 0; rp < 2; ++rp) {                \
      unsigned pk_ = finp[mt][nt][rp];                                        \
      float lo = bf2f(pk_ & 0xffffu) +                                        \
                 pw_ * fmaxf(acc[C][mt][nt][2 * rp] + bv[nt], 0.f);           \
      float hi = bf2f(pk_ >> 16) +                                            \
                 pw_ * fmaxf(acc[C][mt][nt][2 * rp + 1] + bv[nt], 0.f);       \
      finp[mt][nt][rp] = ((unsigned)f2bf(hi) << 16) | (unsigned)f2bf(lo);     \
    }                                                                         \
  }

#define PASS_BODY(KPA, KPB, TAPA, TAPB)                                       \
  {                                                                           \
    floatx4 acc[2][2][4];                                                     \
    _Pragma("unroll") for (int c = 0; c < 2; ++c)                             \
      _Pragma("unroll") for (int mt = 0; mt < 2; ++mt)                        \
        _Pragma("unroll") for (int nt = 0; nt < 4; ++nt)                      \
          acc[c][mt][nt] = (floatx4)0.0f;                                     \
    _Pragma("unroll 1") for (int di = 0; di < 3; ++di) {                      \
      const int so = di - 1;                                                  \
      (void)so;                                                               \
      _Pragma("unroll") for (int dj = 0; dj < 3; ++dj) {                      \
        LOAD_BFR(di, dj)                                                      \
        int bad0 = (dj == 0) ? eLo0 : (dj == 2) ? eHi0 : 0;                   \
        int bad1 = (dj == 0) ? eLo1 : (dj == 2) ? eHi1 : 0;                   \
        TAPA TAPB                                                             \
      }                                                                       \
    }                                                                         \
    FOLDP(0, KPA) FOLDP(1, KPB)                                               \
  }

  // pass 0: kp0 (q=512, paired-window) + kp1 (q=10)
  PASS_BODY(0, 1,
            if (di == 1) { DO_TAP(0, 0, ownw, base + 11 + dj) }
            else if (di == dOther) { DO_TAP(0, 0, othw, base + 11 + dj) },
            DO_TAP(1, 1, ownw, base + 12 + so * 10 + dj - 1))
  // pass 1: kp2 (q=5) + kp3 (q=4)
  PASS_BODY(2, 3,
            DO_TAP(0, 2, ownw, base + 12 + so * 5 + dj - 1),
            DO_TAP(1, 3, ownw, base + 12 + so * 4 + dj - 1))
  // pass 2: kp4 (q=3) + kp5 (q=2)
  PASS_BODY(4, 5,
            DO_TAP(0, 4, ownw, base + 12 + so * 3 + dj - 1),
            DO_TAP(1, 5, ownw, base + 12 + so * 2 + dj - 1))
#undef PASS_BODY
#undef DO_TAP
#undef LOAD_BFR
#undef FOLDP
#undef MFMA16

  // write out + residual (C/D layout: col = lane&15, row = (lane>>4)*4 + r)
#pragma unroll
  for (int mt = 0; mt < 2; ++mt) {
#pragma unroll
    for (int nt = 0; nt < 4; ++nt) {
      int row = rtb + mt * 16 + ((tid >> 4) & 3) * 4;
      int col = nt * 16 + l15;
      size_t bp = ((size_t)bh * 1024 + row) * 64 + col;
#pragma unroll
      for (int rp = 0; rp < 2; ++rp) {
        unsigned pk_ = finp[mt][nt][rp];
        out[bp + (size_t)(2 * rp) * 64] =
            bf2f(pk_ & 0xffffu) + x[bp + (size_t)(2 * rp) * 64];
        out[bp + (size_t)(2 * rp + 1) * 64] =
            bf2f(pk_ >> 16) + x[bp + (size_t)(2 * rp + 1) * 64];
      }
    }
  }
}

extern "C" void kernel_launch(void* const* d_in, const int* in_sizes, int n_in,
                              void* d_out, int out_size, void* d_ws,
                              size_t ws_size, hipStream_t stream) {
  const float* x = (const float*)d_in[0];
  const float* W = (const float*)d_in[1];
  const float* b = (const float*)d_in[2];
  float* out = (float*)d_out;
  float* pwbuf = (float*)d_ws;                                  // 6144 B
  unsigned short* wt2 = (unsigned short*)((char*)d_ws + 8192);  // 73728 B

  pw_kernel<<<dim3(256 + 18), dim3(512), 0, stream>>>(x, pwbuf, W, wt2);
  conv_kernel<<<dim3(8, 256), dim3(256), 0, stream>>>(x, wt2, b, pwbuf, out);
}

// Round 18
// 122.321 us; speedup vs baseline: 1.4442x; 1.4442x over previous
//
#include <hip/hip_runtime.h>

typedef __attribute__((ext_vector_type(8))) short bhalf8;
typedef __attribute__((ext_vector_type(4))) float floatx4;

#define NF 6  // freq_list = [1,103,205,307,409,511] -> periods [2,104,206,308,410,512]

__device__ __forceinline__ unsigned short f2bf(float f) {
  unsigned u = __float_as_uint(f);
  u += 0x7FFFu + ((u >> 16) & 1u);
  return (unsigned short)(u >> 16);
}

// ------- kernel 1: period weights (6-freq DFT + softmax) + fused W-prep ----
__global__ __launch_bounds__(512) void pw_kernel(const float* __restrict__ x,
                                                 float* __restrict__ pwbuf,
                                                 const float* __restrict__ W,
                                                 unsigned short* __restrict__ wt_img) {
  const int tid = threadIdx.x;
  if (blockIdx.x >= 256) {  // ---- prep_w path ----
    if (tid < 256) {
      int task = (blockIdx.x - 256) * 256 + tid;  // 9*64*8 = 4608 tasks
      int didj = task >> 9;
      int fo = (task >> 3) & 63;
      int c = task & 7;
      int cs = c ^ (fo & 7);
      bhalf8 pk;
#pragma unroll
      for (int j = 0; j < 8; ++j) {
        int fi = cs * 8 + j;
        pk[j] = (short)f2bf(W[(size_t)(didj * 64 + fi) * 64 + fo]);
      }
      *(bhalf8*)((char*)wt_img + (size_t)didj * 8192 + fo * 128 + c * 16) = pk;
    }
    return;
  }
  const int bh = blockIdx.x;
  const int w = tid >> 6;
  const int f = tid & 63;
  const int t0w = w * 128;
  const float* xb = x + (size_t)bh * 65536 + f;

  const float STEP = -6.283185307179586f / 1024.0f;
  float re[NF], im[NF], c[NF], s[NF], ck[NF], sk[NF];
#pragma unroll
  for (int k = 0; k < NF; ++k) {
    int freq = 1 + 102 * k;
    int ph0 = (freq * t0w) & 1023;
    __sincosf((float)ph0 * STEP, &s[k], &c[k]);
    __sincosf((float)freq * STEP, &sk[k], &ck[k]);
    re[k] = 0.f;
    im[k] = 0.f;
  }
#pragma unroll 4
  for (int t = 0; t < 128; ++t) {
    float v = xb[(size_t)(t0w + t) * 64];
#pragma unroll
    for (int k = 0; k < NF; ++k) {
      re[k] = fmaf(v, c[k], re[k]);
      im[k] = fmaf(v, s[k], im[k]);
      float cn = fmaf(c[k], ck[k], -s[k] * sk[k]);
      float sn = fmaf(c[k], sk[k], s[k] * ck[k]);
      c[k] = cn;
      s[k] = sn;
    }
  }
  __shared__ float part[8][NF][64][2];  // 24 KB
#pragma unroll
  for (int k = 0; k < NF; ++k) {
    part[w][k][f][0] = re[k];
    part[w][k][f][1] = im[k];
  }
  __syncthreads();
  if (tid < 64) {
    float sm[NF];
#pragma unroll
    for (int k = 0; k < NF; ++k) {
      float rr = 0.f, ii = 0.f;
#pragma unroll
      for (int ww = 0; ww < 8; ++ww) {
        rr += part[ww][k][tid][0];
        ii += part[ww][k][tid][1];
      }
      float amp = sqrtf(rr * rr + ii * ii);
#pragma unroll
      for (int off = 32; off > 0; off >>= 1) amp += __shfl_xor(amp, off);
      sm[k] = amp * (1.0f / 64.0f);
    }
    if (tid == 0) {
      float m = sm[0];
#pragma unroll
      for (int i = 1; i < NF; ++i) m = fmaxf(m, sm[i]);
      float e[NF], ssum = 0.f;
#pragma unroll
      for (int i = 0; i < NF; ++i) {
        e[i] = __expf(sm[i] - m);
        ssum += e[i];
      }
      float inv = 1.0f / ssum;
#pragma unroll
      for (int i = 0; i < NF; ++i) pwbuf[bh * NF + i] = e[i] * inv;
    }
  }
}

// ---------------- kernel 3: fused 6-period conv + relu + weighted sum + x --
// Paired-window blocks: block covers rows [t0,t0+128) u [512+t0,512+t0+128),
// 8 waves of 32 rows x 64 cols (g = wid>>2 selects half); kp0 (p=2,q=512)
// far taps land in the partner window. All 9 swizzled W tiles in LDS.
// Two passes of 3 periods bound live accumulators (acc[3][2][4]=96 AGPR +
// ~128 VGPR fits the 256-reg cap of 2 waves/SIMD). dj fully unrolled (3x)
// for scheduling window; di runtime (anti-spill). Masked edge taps redirect
// their LDS A-read to a zero row.
__global__ __launch_bounds__(512, 2) void conv_kernel(
    const float* __restrict__ x, const unsigned short* __restrict__ wt_img,
    const float* __restrict__ bias, const float* __restrict__ pwbuf,
    float* __restrict__ out) {
  __shared__ __align__(16) unsigned short win[2][152 * 64];  // 38912 B
  __shared__ __align__(16) unsigned short wl[9 * 64 * 64];   // 73728 B
  __shared__ __align__(16) unsigned short zrow[64];          // 128 B

  const int tid = threadIdx.x;
  const int bh = blockIdx.y;
  const int t0 = blockIdx.x * 128;
  const float* xbh = x + (size_t)bh * (1024 * 64);

  // ---- stage both windows: window w row trel <-> t' = w*512 + t0 - 12 + trel
  {
    const int fi0 = (tid & 7) * 8;
#pragma unroll
    for (int w = 0; w < 2; ++w) {
      int tbase = w * 512 + t0 - 12;
#pragma unroll
      for (int rr = 0; rr < 3; ++rr) {
        int trel = (tid >> 3) + rr * 64;
        if (trel < 152) {
          int tp = tbase + trel;
          float va[8];
          if ((unsigned)tp < 1024u) {
            const float4* src = (const float4*)(xbh + (size_t)tp * 64 + fi0);
            float4 u0 = src[0], u1 = src[1];
            va[0] = u0.x; va[1] = u0.y; va[2] = u0.z; va[3] = u0.w;
            va[4] = u1.x; va[5] = u1.y; va[6] = u1.z; va[7] = u1.w;
          } else {
#pragma unroll
            for (int j = 0; j < 8; ++j) va[j] = 0.f;
          }
          bhalf8 pk;
#pragma unroll
          for (int j = 0; j < 8; ++j) pk[j] = (short)f2bf(va[j]);
          *(bhalf8*)((char*)win[w] + (trel << 7) +
                     ((fi0 * 2) ^ ((trel & 7) << 4))) = pk;
        }
      }
    }
    // ---- stage all 9 swizzled W tiles: 8192B/tile = 512 threads x 16B
#pragma unroll
    for (int d = 0; d < 9; ++d) {
      const char* src = (const char*)wt_img + (size_t)d * 8192;
      char* dst = (char*)wl + (size_t)d * 8192;
      *(bhalf8*)(dst + tid * 16) = *(const bhalf8*)(src + tid * 16);
    }
    if (tid < 8) *(bhalf8*)((char*)zrow + tid * 16) = (bhalf8)0;
  }
  __syncthreads();  // the only barrier

  const int l15 = tid & 15;
  const int l4x16 = ((tid >> 4) & 3) * 16;
  const int wid = tid >> 6;
  const int g = wid >> 2;          // which t-half this wave outputs
  const int wr = wid & 3;          // row group within the half
  const int rtb = g * 512 + t0 + wr * 32;
  const int dOther = g ? 0 : 2;    // the di whose kp0 tap is in partner window
  const char* ownw = (const char*)win[g];
  const char* othw = (const char*)win[1 - g];
  const char* zb = (const char*)zrow;

  // pre-packed per-lane edge bits: bit kp set iff col j==0 (eLo) / j==q-1 (eHi)
  const int rt0 = rtb + l15, rt1 = rt0 + 16;
  int eLo0 = 0, eHi0 = 0, eLo1 = 0, eHi1 = 0;
  {
    int j0, j1;
    j0 = rt0 & 511; j1 = rt1 & 511;
    eLo0 |= (j0 == 0) << 0;   eHi0 |= (j0 == 511) << 0;
    eLo1 |= (j1 == 0) << 0;   eHi1 |= (j1 == 511) << 0;
    j0 = rt0 % 10;  j1 = rt1 % 10;
    eLo0 |= (j0 == 0) << 1;   eHi0 |= (j0 == 9) << 1;
    eLo1 |= (j1 == 0) << 1;   eHi1 |= (j1 == 9) << 1;
    j0 = rt0 % 5;   j1 = rt1 % 5;
    eLo0 |= (j0 == 0) << 2;   eHi0 |= (j0 == 4) << 2;
    eLo1 |= (j1 == 0) << 2;   eHi1 |= (j1 == 4) << 2;
    j0 = rt0 & 3;   j1 = rt1 & 3;
    eLo0 |= (j0 == 0) << 3;   eHi0 |= (j0 == 3) << 3;
    eLo1 |= (j1 == 0) << 3;   eHi1 |= (j1 == 3) << 3;
    j0 = rt0 % 3;   j1 = rt1 % 3;
    eLo0 |= (j0 == 0) << 4;   eHi0 |= (j0 == 2) << 4;
    eLo1 |= (j1 == 0) << 4;   eHi1 |= (j1 == 2) << 4;
    j0 = rt0 & 1;   j1 = rt1 & 1;
    eLo0 |= (j0 == 0) << 5;   eHi0 |= (j0 == 1) << 5;
    eLo1 |= (j1 == 0) << 5;   eHi1 |= (j1 == 1) << 5;
  }

  float pwv[NF];
#pragma unroll
  for (int kp = 0; kp < NF; ++kp) pwv[kp] = pwbuf[bh * NF + kp];
  float bv[4];
#pragma unroll
  for (int nt = 0; nt < 4; ++nt) bv[nt] = bias[nt * 16 + l15];

  floatx4 fin[2][4];
#pragma unroll
  for (int mt = 0; mt < 2; ++mt)
#pragma unroll
    for (int nt = 0; nt < 4; ++nt) fin[mt][nt] = (floatx4)0.0f;

  const int base = wr * 32 + l15;

#define DO_TAP(C, KP, BUFBASE, R0)                                            \
  {                                                                           \
    int r0_ = (R0), r1_ = r0_ + 16;                                           \
    const char* pa0 = (((bad0 >> (KP)) & 1) == 0)                             \
                          ? (const char*)(BUFBASE) + (r0_ << 7) : zb;         \
    const char* pa1 = (((bad1 >> (KP)) & 1) == 0)                             \
                          ? (const char*)(BUFBASE) + (r1_ << 7) : zb;         \
    int sw0 = (r0_ & 7) << 4, sw1 = (r1_ & 7) << 4;                           \
    _Pragma("unroll") for (int kk = 0; kk < 2; ++kk) {                        \
      int kb = kk * 64 + l4x16;                                               \
      bhalf8 a0 = *(const bhalf8*)(pa0 + (kb ^ sw0));                         \
      bhalf8 a1 = *(const bhalf8*)(pa1 + (kb ^ sw1));                         \
      _Pragma("unroll") for (int nt = 0; nt < 4; ++nt) {                      \
        acc[C][0][nt] = __builtin_amdgcn_mfma_f32_16x16x32_bf16(              \
            a0, bfr[kk][nt], acc[C][0][nt], 0, 0, 0);                         \
        acc[C][1][nt] = __builtin_amdgcn_mfma_f32_16x16x32_bf16(              \
            a1, bfr[kk][nt], acc[C][1][nt], 0, 0, 0);                         \
      }                                                                       \
    }                                                                         \
  }

#define LOAD_BFR                                                              \
  bhalf8 bfr[2][4];                                                           \
  {                                                                           \
    const char* wt = (const char*)wl + (size_t)(di * 3 + dj) * 8192;          \
    _Pragma("unroll") for (int kk = 0; kk < 2; ++kk)                          \
        _Pragma("unroll") for (int nt = 0; nt < 4; ++nt) {                    \
      int fo = nt * 16 + l15;                                                 \
      bfr[kk][nt] = *(const bhalf8*)(wt + (fo << 7) +                         \
                                     ((kk * 64 + l4x16) ^ ((fo & 7) << 4)));  \
    }                                                                         \
  }

#define FOLD(C, KP)                                                           \
  _Pragma("unroll") for (int mt = 0; mt < 2; ++mt)                            \
      _Pragma("unroll") for (int nt = 0; nt < 4; ++nt)                        \
          _Pragma("unroll") for (int r = 0; r < 4; ++r)                       \
              fin[mt][nt][r] = fmaf(                                          \
                  pwv[KP], fmaxf(acc[C][mt][nt][r] + bv[nt], 0.f),            \
                  fin[mt][nt][r]);

  // ---------------- pass 0: kp 0,1,2 ----------------
  {
    floatx4 acc[3][2][4];
#pragma unroll
    for (int c = 0; c < 3; ++c)
#pragma unroll
      for (int mt = 0; mt < 2; ++mt)
#pragma unroll
        for (int nt = 0; nt < 4; ++nt) acc[c][mt][nt] = (floatx4)0.0f;
#pragma unroll 1
    for (int di = 0; di < 3; ++di) {
#pragma unroll
      for (int dj = 0; dj < 3; ++dj) {
        LOAD_BFR
        int bad0 = (dj == 0) ? eLo0 : (dj == 2) ? eHi0 : 0;
        int bad1 = (dj == 0) ? eLo1 : (dj == 2) ? eHi1 : 0;
        if (di == 1) {
          DO_TAP(0, 0, ownw, base + 11 + dj)
        } else if (di == dOther) {
          DO_TAP(0, 0, othw, base + 11 + dj)
        }
        const int so = di - 1;
        DO_TAP(1, 1, ownw, base + 12 + so * 10 + dj - 1)
        DO_TAP(2, 2, ownw, base + 12 + so * 5 + dj - 1)
      }
    }
    FOLD(0, 0) FOLD(1, 1) FOLD(2, 2)
  }

  // ---------------- pass 1: kp 3,4,5 ----------------
  {
    floatx4 acc[3][2][4];
#pragma unroll
    for (int c = 0; c < 3; ++c)
#pragma unroll
      for (int mt = 0; mt < 2; ++mt)
#pragma unroll
        for (int nt = 0; nt < 4; ++nt) acc[c][mt][nt] = (floatx4)0.0f;
#pragma unroll 1
    for (int di = 0; di < 3; ++di) {
#pragma unroll
      for (int dj = 0; dj < 3; ++dj) {
        LOAD_BFR
        int bad0 = (dj == 0) ? eLo0 : (dj == 2) ? eHi0 : 0;
        int bad1 = (dj == 0) ? eLo1 : (dj == 2) ? eHi1 : 0;
        const int so = di - 1;
        DO_TAP(0, 3, ownw, base + 12 + so * 4 + dj - 1)
        DO_TAP(1, 4, ownw, base + 12 + so * 3 + dj - 1)
        DO_TAP(2, 5, ownw, base + 12 + so * 2 + dj - 1)
      }
    }
    FOLD(0, 3) FOLD(1, 4) FOLD(2, 5)
  }
#undef DO_TAP
#undef LOAD_BFR
#undef FOLD

  // write out + residual (C/D layout: col = lane&15, row = (lane>>4)*4 + r)
#pragma unroll
  for (int mt = 0; mt < 2; ++mt) {
#pragma unroll
    for (int nt = 0; nt < 4; ++nt) {
      int row = rtb + mt * 16 + ((tid >> 4) & 3) * 4;
      int col = nt * 16 + l15;
      size_t basep = ((size_t)bh * 1024 + row) * 64 + col;
#pragma unroll
      for (int r = 0; r < 4; ++r) {
        out[basep + (size_t)r * 64] =
            fin[mt][nt][r] + x[basep + (size_t)r * 64];
      }
    }
  }
}

extern "C" void kernel_launch(void* const* d_in, const int* in_sizes, int n_in,
                              void* d_out, int out_size, void* d_ws,
                              size_t ws_size, hipStream_t stream) {
  const float* x = (const float*)d_in[0];
  const float* W = (const float*)d_in[1];
  const float* b = (const float*)d_in[2];
  float* out = (float*)d_out;
  float* pwbuf = (float*)d_ws;                                    // 6144 B
  unsigned short* wt_img = (unsigned short*)((char*)d_ws + 8192); // 73728 B

  pw_kernel<<<dim3(256 + 18), dim3(512), 0, stream>>>(x, pwbuf, W, wt_img);
  conv_kernel<<<dim3(4, 256), dim3(512), 0, stream>>>(x, wt_img, b, pwbuf, out);
}